// Round 4
// baseline (408.980 us; speedup 1.0000x reference)
//
#include <hip/hip_runtime.h>

#define EPS_BN 1e-5f

typedef float f32x4 __attribute__((ext_vector_type(4)));

// Padded plane geometry: logical rows -1..32 at index r+1 (34 rows),
// logical cols -1..34 at index c+1 (36 cols). Reading 6 cols starting at
// logical col c4-1 begins at index c4 -> 16B aligned (c4 multiple of 4).
#define PROWS 34
#define PCOLS 36
#define PS (PROWS * PCOLS)   // 1224 floats per plane

// ---------------------------------------------------------------------------
// Copy raw (P,32,32) input into padded (P,34,36) buffer (borders pre-zeroed
// by the launch-time memset).
// ---------------------------------------------------------------------------
__global__ __launch_bounds__(256) void pad_copy_kern(
    const float* __restrict__ x, float* __restrict__ bufX)
{
    const int plane = blockIdx.x;
    const int tid = threadIdx.x;
    const int r  = tid >> 3;
    const int c4 = (tid & 7) << 2;
    float4 v = *(const float4*)(x + (plane << 10) + (r << 5) + c4);
    float* o = bufX + plane * PS + (r + 1) * PCOLS + (c4 + 1);
    o[0] = v.x; o[1] = v.y; o[2] = v.z; o[3] = v.w;
}

// ---------------------------------------------------------------------------
// Pure 3x3 SAME conv over a ci-CHUNK, partial accumulation.
// Grid = (4 chunks) x (4 n) x (COUT co) -> 4 blocks/CU on the 64-co layers
// (4 waves/SIMD, vs 1 in the fused design). Thread = 4-px horizontal strip
// (r = tid>>3, cols c4..c4+3) with aligned float4/float2 loads (6 VMEM
// instr per ci). Input buffer holds post-BN-ReLU values with TRUE zero
// pads, so no border correction and no BN in the inner loop: 36 fmaf/ci.
// Writes partial[chunk][n*COUT+co][1024] (flat, float4).
// part lives in the att region of d_out (dead until attention runs), so
// d_ws usage stays identical to the previously verified kernel.
// ---------------------------------------------------------------------------
template<int CI_CHUNK, int CIN, int COUT>
__global__ __launch_bounds__(256) void conv3x3_part(
    const float* __restrict__ in,    // padded (4, CIN, 34, 36), zero pads
    const float* __restrict__ wgt,   // (COUT, CIN, 3, 3)
    float* __restrict__ part)        // (4, 4*COUT, 1024)
{
    const int tid = threadIdx.x;
    const int b   = blockIdx.x;
    const int PL4   = 4 * COUT;
    const int chunk = b / PL4;
    const int rem   = b - chunk * PL4;
    const int n     = rem / COUT;
    const int co    = rem - n * COUT;
    const int ci0   = chunk * CI_CHUNK;

    const int r  = tid >> 3;             // 0..31
    const int c4 = (tid & 7) << 2;       // 0,4,..,28
    // points at padded (row r-1, col c4-1) = index (r, c4)
    const float* ip  = in + (n * CIN + ci0) * PS + r * PCOLS + c4;
    const float* wp0 = wgt + (co * CIN + ci0) * 9;

    float acc0 = 0.f, acc1 = 0.f, acc2 = 0.f, acc3 = 0.f;

    #pragma unroll 4
    for (int ci = 0; ci < CI_CHUNK; ++ci) {
        const float* p  = ip + ci * PS;
        const float* wp = wp0 + ci * 9;          // block-uniform -> s_load
        #pragma unroll
        for (int dr = 0; dr < 3; ++dr) {
            float4 a  = *(const float4*)(p + dr * PCOLS);
            float2 bb = *(const float2*)(p + dr * PCOLS + 4);
            float wa = wp[dr * 3 + 0], wb = wp[dr * 3 + 1], wc = wp[dr * 3 + 2];
            acc0 = fmaf(wa, a.x, fmaf(wb, a.y, fmaf(wc, a.z, acc0)));
            acc1 = fmaf(wa, a.y, fmaf(wb, a.z, fmaf(wc, a.w, acc1)));
            acc2 = fmaf(wa, a.z, fmaf(wb, a.w, fmaf(wc, bb.x, acc2)));
            acc3 = fmaf(wa, a.w, fmaf(wb, bb.x, fmaf(wc, bb.y, acc3)));
        }
    }

    f32x4 res; res.x = acc0; res.y = acc1; res.z = acc2; res.w = acc3;
    *((f32x4*)part + (b << 8) + tid) = res;      // px = tid*4 (strip layout)
}

// ---------------------------------------------------------------------------
// Combine 4 ci-chunk partials + bias -> raw u. Optionally accumulate BN
// stats (sum/sumsq atomics) and write into padded buffer interior
// (PAD_OUT) or flat 1024 layout (regressor -> xf).
// One block per plane (n,co); thread = 4 consecutive px (float4 loads).
// ---------------------------------------------------------------------------
template<int COUT, bool STATS, bool PAD_OUT>
__global__ __launch_bounds__(256) void combine_kern(
    const float* __restrict__ part,   // (4, 4*COUT, 1024)
    const float* __restrict__ bias,   // (COUT)
    float* __restrict__ out,          // padded (4*COUT, PS) or flat
    float* __restrict__ out_stats)    // (2, 64)
{
    const int tid = threadIdx.x;
    const int p   = blockIdx.x;                  // plane = n*COUT+co
    const int NP  = 4 * COUT;
    const int co  = p - (p / COUT) * COUT;       // p % COUT

    const float4* pp = (const float4*)part + (p << 8) + tid;
    const int cs = NP << 8;                      // chunk stride in float4
    float4 a = pp[0];
    float4 b = pp[cs];
    float4 c = pp[2 * cs];
    float4 d = pp[3 * cs];
    const float bv = bias[co];
    float u0 = ((a.x + b.x) + (c.x + d.x)) + bv;
    float u1 = ((a.y + b.y) + (c.y + d.y)) + bv;
    float u2 = ((a.z + b.z) + (c.z + d.z)) + bv;
    float u3 = ((a.w + b.w) + (c.w + d.w)) + bv;

    if (PAD_OUT) {
        const int r  = tid >> 3;
        const int c4 = (tid & 7) << 2;
        float* o = out + p * PS + (r + 1) * PCOLS + (c4 + 1);
        o[0] = u0; o[1] = u1; o[2] = u2; o[3] = u3;
    } else {
        f32x4 res; res.x = u0; res.y = u1; res.z = u2; res.w = u3;
        *((f32x4*)out + (p << 8) + tid) = res;
    }

    if (STATS) {
        float s  = u0 + u1 + u2 + u3;
        float ss = u0 * u0 + u1 * u1 + u2 * u2 + u3 * u3;
        #pragma unroll
        for (int off = 32; off; off >>= 1) {
            s  += __shfl_down(s,  off);
            ss += __shfl_down(ss, off);
        }
        if ((tid & 63) == 0) {
            atomicAdd(&out_stats[co],      s);
            atomicAdd(&out_stats[64 + co], ss);
        }
    }
}

// ---------------------------------------------------------------------------
// In-place BN (batch stats) + ReLU on the padded buffer interior.
// After this, the buffer holds h with genuinely-zero pads -> next conv
// needs no BN and no border correction. One block per plane.
// ---------------------------------------------------------------------------
__global__ __launch_bounds__(256) void bnrelu_kern(
    float* __restrict__ buf,           // padded (256, PS), in place
    const float* __restrict__ stats,   // (2, 64)
    const float* __restrict__ gamma,   // (64)
    const float* __restrict__ beta)    // (64)
{
    const int tid = threadIdx.x;
    const int p   = blockIdx.x;
    const int ch  = p & 63;

    const float s    = stats[ch];
    const float ss   = stats[64 + ch];
    const float mean = s * (1.0f / 4096.0f);
    const float var  = fmaxf(ss * (1.0f / 4096.0f) - mean * mean, 0.0f);
    const float g    = gamma[ch] * rsqrtf(var + EPS_BN);
    const float sh   = beta[ch] - mean * g;

    const int r  = tid >> 3;
    const int c4 = (tid & 7) << 2;
    float* o = buf + p * PS + (r + 1) * PCOLS + (c4 + 1);
    o[0] = fmaxf(fmaf(g, o[0], sh), 0.f);
    o[1] = fmaxf(fmaf(g, o[1], sh), 0.f);
    o[2] = fmaxf(fmaf(g, o[2], sh), 0.f);
    o[3] = fmaxf(fmaf(g, o[3], sh), 0.f);
}

// ---------------------------------------------------------------------------
// Hadamard attention. One block per (t,i); att_w row read once, reused for
// all 4 batch images. No max-subtraction (|scores| < 1 by construction:
// |att_w| <= 0.054 xavier limit, |xf| ~ O(5)), so a single fused
// sum/dot reduction round suffices (2 barriers total). att written with
// nontemporal native-vector stores (201 MB, never re-read).
// ---------------------------------------------------------------------------
__global__ __launch_bounds__(256) void attention_v2(
    const float* __restrict__ xf,     // (4,12,1024)
    const float* __restrict__ att_w,  // (12,1024,1024)
    float* __restrict__ out,          // (4,12,1024)
    float* __restrict__ att)          // (4,12,1024,1024)
{
    __shared__ __align__(16) float s_xf[4096];
    __shared__ float red[4][8];       // [wave][ps0..3, pd0..3]
    const int tid = threadIdx.x;
    const int t   = blockIdx.x >> 10;
    const int i   = blockIdx.x & 1023;
    const int w   = tid >> 6;

    const float4* xf4 = (const float4*)xf;
    float4* s4 = (float4*)s_xf;
    #pragma unroll
    for (int q = 0; q < 4; ++q) {
        int e  = (q << 8) + tid;
        int nn = e >> 8;
        int j4 = e & 255;
        s4[e] = xf4[((nn * 12 + t) << 8) + j4];
    }
    float4 wv = ((const float4*)att_w)[(((t << 10) + i) << 8) + tid];
    __syncthreads();

    float ev[4][4], ps[4], pd[4];
    #pragma unroll
    for (int nn = 0; nn < 4; ++nn) {
        float4 xv = ((const float4*)(s_xf + (nn << 10)))[tid];
        float e0 = __expf(wv.x * xv.x);
        float e1 = __expf(wv.y * xv.y);
        float e2 = __expf(wv.z * xv.z);
        float e3 = __expf(wv.w * xv.w);
        ps[nn] = (e0 + e1) + (e2 + e3);
        pd[nn] = fmaf(e0, xv.x, fmaf(e1, xv.y, fmaf(e2, xv.z, e3 * xv.w)));
        ev[nn][0] = e0; ev[nn][1] = e1; ev[nn][2] = e2; ev[nn][3] = e3;
    }
    #pragma unroll
    for (int off = 32; off; off >>= 1) {
        #pragma unroll
        for (int nn = 0; nn < 4; ++nn) {
            ps[nn] += __shfl_down(ps[nn], off);
            pd[nn] += __shfl_down(pd[nn], off);
        }
    }
    if ((tid & 63) == 0) {
        #pragma unroll
        for (int nn = 0; nn < 4; ++nn) {
            red[w][nn]     = ps[nn];
            red[w][4 + nn] = pd[nn];
        }
    }
    __syncthreads();

    #pragma unroll
    for (int nn = 0; nn < 4; ++nn) {
        float sum = (red[0][nn] + red[1][nn]) + (red[2][nn] + red[3][nn]);
        float dot = (red[0][4+nn] + red[1][4+nn]) + (red[2][4+nn] + red[3][4+nn]);
        float inv = 1.0f / sum;
        f32x4 av;
        av.x = ev[nn][0] * inv; av.y = ev[nn][1] * inv;
        av.z = ev[nn][2] * inv; av.w = ev[nn][3] * inv;
        f32x4* dst = (f32x4*)att + ((((nn * 12 + t) << 10) + i) << 8) + tid;
        __builtin_nontemporal_store(av, dst);
        if (tid == 0) out[((nn * 12 + t) << 10) + i] = dot * inv;
    }
}

extern "C" void kernel_launch(void* const* d_in, const int* in_sizes, int n_in,
                              void* d_out, int out_size, void* d_ws, size_t ws_size,
                              hipStream_t stream)
{
    const float* x      = (const float*)d_in[0];
    const float* conv0w = (const float*)d_in[1];  // (64,12,3,3)
    const float* convw  = (const float*)d_in[2];  // (4,64,64,3,3)
    const float* convb  = (const float*)d_in[3];  // (5,64)
    const float* gammas = (const float*)d_in[4];  // (5,64)
    const float* betas  = (const float*)d_in[5];  // (5,64)
    const float* regw   = (const float*)d_in[6];  // (12,64,3,3)
    const float* regb   = (const float*)d_in[7];  // (12)
    const float* attw   = (const float*)d_in[8];  // (12,1024,1024)

    float* out = (float*)d_out;                   // (4,12,32,32)
    float* att = out + 4 * 12 * 1024;             // (4,12,1024,1024)

    float* ws    = (float*)d_ws;
    float* stats = ws;                            // 5 x 128
    float* bufX  = stats + 640;                   // (48, PS) padded input
    float* bufA  = bufX + 48 * PS;                // (256, PS) padded
    float* bufB  = bufA + 256 * PS;               // (256, PS) padded
    float* xf    = bufB + 256 * PS;               // (4,12,1024) flat
    // ci-chunk partials live in the att region of d_out (4 MB of its
    // 201 MB), dead by the time attention_v2 runs -> d_ws footprint is
    // byte-identical to the previously harness-verified kernel.
    float* part  = att;                           // (4, 4*COUT, 1024)

    // zero stats + all padded buffers (borders must be 0; ws is poisoned).
    // part/xf are fully overwritten -> no zeroing needed.
    (void)hipMemsetAsync(stats, 0,
                         (640 + 48 * PS + 2 * 256 * PS) * sizeof(float),
                         stream);

    pad_copy_kern<<<48, 256, 0, stream>>>(x, bufX);

    // ---- layer 0: conv 12->64 (3 ci per chunk), stats0, bn0 -> bufA holds h0
    conv3x3_part<3, 12, 64><<<1024, 256, 0, stream>>>(bufX, conv0w, part);
    combine_kern<64, true, true><<<256, 256, 0, stream>>>(part, convb, bufA, stats);
    bnrelu_kern<<<256, 256, 0, stream>>>(bufA, stats, gammas, betas);

    // ---- layer 1: bufA -> bufB
    conv3x3_part<16, 64, 64><<<1024, 256, 0, stream>>>(bufA, convw + 0 * 36864, part);
    combine_kern<64, true, true><<<256, 256, 0, stream>>>(part, convb + 64, bufB, stats + 128);
    bnrelu_kern<<<256, 256, 0, stream>>>(bufB, stats + 128, gammas + 64, betas + 64);

    // ---- layer 2: bufB -> bufA
    conv3x3_part<16, 64, 64><<<1024, 256, 0, stream>>>(bufB, convw + 1 * 36864, part);
    combine_kern<64, true, true><<<256, 256, 0, stream>>>(part, convb + 128, bufA, stats + 256);
    bnrelu_kern<<<256, 256, 0, stream>>>(bufA, stats + 256, gammas + 128, betas + 128);

    // ---- layer 3: bufA -> bufB
    conv3x3_part<16, 64, 64><<<1024, 256, 0, stream>>>(bufA, convw + 2 * 36864, part);
    combine_kern<64, true, true><<<256, 256, 0, stream>>>(part, convb + 192, bufB, stats + 384);
    bnrelu_kern<<<256, 256, 0, stream>>>(bufB, stats + 384, gammas + 192, betas + 192);

    // ---- layer 4: bufB -> bufA
    conv3x3_part<16, 64, 64><<<1024, 256, 0, stream>>>(bufB, convw + 3 * 36864, part);
    combine_kern<64, true, true><<<256, 256, 0, stream>>>(part, convb + 256, bufA, stats + 512);
    bnrelu_kern<<<256, 256, 0, stream>>>(bufA, stats + 512, gammas + 256, betas + 256);

    // ---- regressor: 64 -> 12, bufA -> xf (flat), no stats/bn
    conv3x3_part<16, 64, 12><<<192, 256, 0, stream>>>(bufA, regw, part);
    combine_kern<12, false, false><<<48, 256, 0, stream>>>(part, regb, xf, nullptr);

    attention_v2<<<12288, 256, 0, stream>>>(xf, attw, out, att);
}

// Round 5
// 407.670 us; speedup vs baseline: 1.0032x; 1.0032x over previous
//
#include <hip/hip_runtime.h>

#define EPS_BN 1e-5f

typedef float f32x4 __attribute__((ext_vector_type(4)));

// Padded plane geometry: logical rows -1..32 at index r+1 (34 rows),
// logical cols -1..34 at index c+1 (36 cols). Reading 6 cols starting at
// logical col c4-1 begins at index c4 -> 16B aligned (c4 multiple of 4).
#define PROWS 34
#define PCOLS 36
#define PS (PROWS * PCOLS)   // 1224 floats per plane

// ---------------------------------------------------------------------------
// Copy raw (P,32,32) input into padded (P,34,36) buffer (borders pre-zeroed
// by the launch-time memset).
// ---------------------------------------------------------------------------
__global__ __launch_bounds__(256) void pad_copy_kern(
    const float* __restrict__ x, float* __restrict__ bufX)
{
    const int plane = blockIdx.x;
    const int tid = threadIdx.x;
    const int r  = tid >> 3;
    const int c4 = (tid & 7) << 2;
    float4 v = *(const float4*)(x + (plane << 10) + (r << 5) + c4);
    float* o = bufX + plane * PS + (r + 1) * PCOLS + (c4 + 1);
    o[0] = v.x; o[1] = v.y; o[2] = v.z; o[3] = v.w;
}

// ---------------------------------------------------------------------------
// Pure 3x3 SAME conv over a ci-CHUNK, partial accumulation.
// (Unchanged from Round 4 — clean A/B: this round touches attention only.)
// ---------------------------------------------------------------------------
template<int CI_CHUNK, int CIN, int COUT>
__global__ __launch_bounds__(256) void conv3x3_part(
    const float* __restrict__ in,    // padded (4, CIN, 34, 36), zero pads
    const float* __restrict__ wgt,   // (COUT, CIN, 3, 3)
    float* __restrict__ part)        // (4, 4*COUT, 1024)
{
    const int tid = threadIdx.x;
    const int b   = blockIdx.x;
    const int PL4   = 4 * COUT;
    const int chunk = b / PL4;
    const int rem   = b - chunk * PL4;
    const int n     = rem / COUT;
    const int co    = rem - n * COUT;
    const int ci0   = chunk * CI_CHUNK;

    const int r  = tid >> 3;             // 0..31
    const int c4 = (tid & 7) << 2;       // 0,4,..,28
    // points at padded (row r-1, col c4-1) = index (r, c4)
    const float* ip  = in + (n * CIN + ci0) * PS + r * PCOLS + c4;
    const float* wp0 = wgt + (co * CIN + ci0) * 9;

    float acc0 = 0.f, acc1 = 0.f, acc2 = 0.f, acc3 = 0.f;

    #pragma unroll 4
    for (int ci = 0; ci < CI_CHUNK; ++ci) {
        const float* p  = ip + ci * PS;
        const float* wp = wp0 + ci * 9;          // block-uniform -> s_load
        #pragma unroll
        for (int dr = 0; dr < 3; ++dr) {
            float4 a  = *(const float4*)(p + dr * PCOLS);
            float2 bb = *(const float2*)(p + dr * PCOLS + 4);
            float wa = wp[dr * 3 + 0], wb = wp[dr * 3 + 1], wc = wp[dr * 3 + 2];
            acc0 = fmaf(wa, a.x, fmaf(wb, a.y, fmaf(wc, a.z, acc0)));
            acc1 = fmaf(wa, a.y, fmaf(wb, a.z, fmaf(wc, a.w, acc1)));
            acc2 = fmaf(wa, a.z, fmaf(wb, a.w, fmaf(wc, bb.x, acc2)));
            acc3 = fmaf(wa, a.w, fmaf(wb, bb.x, fmaf(wc, bb.y, acc3)));
        }
    }

    f32x4 res; res.x = acc0; res.y = acc1; res.z = acc2; res.w = acc3;
    *((f32x4*)part + (b << 8) + tid) = res;      // px = tid*4 (strip layout)
}

// ---------------------------------------------------------------------------
// Combine 4 ci-chunk partials + bias -> raw u. Optionally accumulate BN
// stats (sum/sumsq atomics) and write into padded buffer interior
// (PAD_OUT) or flat 1024 layout (regressor -> xf).
// ---------------------------------------------------------------------------
template<int COUT, bool STATS, bool PAD_OUT>
__global__ __launch_bounds__(256) void combine_kern(
    const float* __restrict__ part,   // (4, 4*COUT, 1024)
    const float* __restrict__ bias,   // (COUT)
    float* __restrict__ out,          // padded (4*COUT, PS) or flat
    float* __restrict__ out_stats)    // (2, 64)
{
    const int tid = threadIdx.x;
    const int p   = blockIdx.x;                  // plane = n*COUT+co
    const int NP  = 4 * COUT;
    const int co  = p - (p / COUT) * COUT;       // p % COUT

    const float4* pp = (const float4*)part + (p << 8) + tid;
    const int cs = NP << 8;                      // chunk stride in float4
    float4 a = pp[0];
    float4 b = pp[cs];
    float4 c = pp[2 * cs];
    float4 d = pp[3 * cs];
    const float bv = bias[co];
    float u0 = ((a.x + b.x) + (c.x + d.x)) + bv;
    float u1 = ((a.y + b.y) + (c.y + d.y)) + bv;
    float u2 = ((a.z + b.z) + (c.z + d.z)) + bv;
    float u3 = ((a.w + b.w) + (c.w + d.w)) + bv;

    if (PAD_OUT) {
        const int r  = tid >> 3;
        const int c4 = (tid & 7) << 2;
        float* o = out + p * PS + (r + 1) * PCOLS + (c4 + 1);
        o[0] = u0; o[1] = u1; o[2] = u2; o[3] = u3;
    } else {
        f32x4 res; res.x = u0; res.y = u1; res.z = u2; res.w = u3;
        *((f32x4*)out + (p << 8) + tid) = res;
    }

    if (STATS) {
        float s  = u0 + u1 + u2 + u3;
        float ss = u0 * u0 + u1 * u1 + u2 * u2 + u3 * u3;
        #pragma unroll
        for (int off = 32; off; off >>= 1) {
            s  += __shfl_down(s,  off);
            ss += __shfl_down(ss, off);
        }
        if ((tid & 63) == 0) {
            atomicAdd(&out_stats[co],      s);
            atomicAdd(&out_stats[64 + co], ss);
        }
    }
}

// ---------------------------------------------------------------------------
// In-place BN (batch stats) + ReLU on the padded buffer interior.
// ---------------------------------------------------------------------------
__global__ __launch_bounds__(256) void bnrelu_kern(
    float* __restrict__ buf,           // padded (256, PS), in place
    const float* __restrict__ stats,   // (2, 64)
    const float* __restrict__ gamma,   // (64)
    const float* __restrict__ beta)    // (64)
{
    const int tid = threadIdx.x;
    const int p   = blockIdx.x;
    const int ch  = p & 63;

    const float s    = stats[ch];
    const float ss   = stats[64 + ch];
    const float mean = s * (1.0f / 4096.0f);
    const float var  = fmaxf(ss * (1.0f / 4096.0f) - mean * mean, 0.0f);
    const float g    = gamma[ch] * rsqrtf(var + EPS_BN);
    const float sh   = beta[ch] - mean * g;

    const int r  = tid >> 3;
    const int c4 = (tid & 7) << 2;
    float* o = buf + p * PS + (r + 1) * PCOLS + (c4 + 1);
    o[0] = fmaxf(fmaf(g, o[0], sh), 0.f);
    o[1] = fmaxf(fmaf(g, o[1], sh), 0.f);
    o[2] = fmaxf(fmaf(g, o[2], sh), 0.f);
    o[3] = fmaxf(fmaf(g, o[3], sh), 0.f);
}

// ---------------------------------------------------------------------------
// Hadamard attention v3: WAVE-PER-ROW. One 64-lane wave owns one (t,i):
// zero __syncthreads, zero LDS, fully independent waves -> stalls hidden
// by TLP instead of being serialized by block-wide barriers.
// Lane l handles j = 256k + 4l .. +3 (k=0..3): every global access is a
// perfectly coalesced float4 (wave covers 1024B contiguous per instr).
// xf read straight from L2 (192 KB total, hot; 201 MB aggregate @ 34.5
// TB/s ~ 6 us, overlapped). Reduction = shfl_xor butterfly (all lanes end
// with the total; no broadcast needed). Plain stores this round (A/B vs
// nontemporal). Same no-max-subtraction softmax math as v2.
// ---------------------------------------------------------------------------
__global__ __launch_bounds__(256) void attention_v3(
    const float* __restrict__ xf,     // (4,12,1024)
    const float* __restrict__ att_w,  // (12,1024,1024)
    float* __restrict__ out,          // (4,12,1024)
    float* __restrict__ att)          // (4,12,1024,1024)
{
    const int tid  = threadIdx.x;
    const int lane = tid & 63;
    const int wg   = (blockIdx.x << 2) + (tid >> 6);   // 0..12287
    const int t    = wg >> 10;
    const int i    = wg & 1023;

    const float4* wrow = (const float4*)att_w + (((t << 10) + i) << 8);
    float4 wv0 = wrow[lane];
    float4 wv1 = wrow[64 + lane];
    float4 wv2 = wrow[128 + lane];
    float4 wv3 = wrow[192 + lane];

    #pragma unroll
    for (int nn = 0; nn < 4; ++nn) {
        const float4* xr = (const float4*)xf + ((nn * 12 + t) << 8);
        float4 e0, e1, e2, e3;
        float ps, pd;
        {
            float4 xv = xr[lane];
            e0.x = __expf(wv0.x * xv.x); e0.y = __expf(wv0.y * xv.y);
            e0.z = __expf(wv0.z * xv.z); e0.w = __expf(wv0.w * xv.w);
            ps = (e0.x + e0.y) + (e0.z + e0.w);
            pd = fmaf(e0.x, xv.x, fmaf(e0.y, xv.y, fmaf(e0.z, xv.z, e0.w * xv.w)));
        }
        {
            float4 xv = xr[64 + lane];
            e1.x = __expf(wv1.x * xv.x); e1.y = __expf(wv1.y * xv.y);
            e1.z = __expf(wv1.z * xv.z); e1.w = __expf(wv1.w * xv.w);
            ps += (e1.x + e1.y) + (e1.z + e1.w);
            pd = fmaf(e1.x, xv.x, fmaf(e1.y, xv.y, fmaf(e1.z, xv.z, fmaf(e1.w, xv.w, pd))));
        }
        {
            float4 xv = xr[128 + lane];
            e2.x = __expf(wv2.x * xv.x); e2.y = __expf(wv2.y * xv.y);
            e2.z = __expf(wv2.z * xv.z); e2.w = __expf(wv2.w * xv.w);
            ps += (e2.x + e2.y) + (e2.z + e2.w);
            pd = fmaf(e2.x, xv.x, fmaf(e2.y, xv.y, fmaf(e2.z, xv.z, fmaf(e2.w, xv.w, pd))));
        }
        {
            float4 xv = xr[192 + lane];
            e3.x = __expf(wv3.x * xv.x); e3.y = __expf(wv3.y * xv.y);
            e3.z = __expf(wv3.z * xv.z); e3.w = __expf(wv3.w * xv.w);
            ps += (e3.x + e3.y) + (e3.z + e3.w);
            pd = fmaf(e3.x, xv.x, fmaf(e3.y, xv.y, fmaf(e3.z, xv.z, fmaf(e3.w, xv.w, pd))));
        }

        #pragma unroll
        for (int off = 32; off; off >>= 1) {
            ps += __shfl_xor(ps, off);
            pd += __shfl_xor(pd, off);
        }
        const float inv = 1.0f / ps;

        float4* dst = (float4*)att + ((((nn * 12 + t) << 10) + i) << 8);
        float4 av;
        av.x = e0.x * inv; av.y = e0.y * inv; av.z = e0.z * inv; av.w = e0.w * inv;
        dst[lane] = av;
        av.x = e1.x * inv; av.y = e1.y * inv; av.z = e1.z * inv; av.w = e1.w * inv;
        dst[64 + lane] = av;
        av.x = e2.x * inv; av.y = e2.y * inv; av.z = e2.z * inv; av.w = e2.w * inv;
        dst[128 + lane] = av;
        av.x = e3.x * inv; av.y = e3.y * inv; av.z = e3.z * inv; av.w = e3.w * inv;
        dst[192 + lane] = av;

        if (lane == 0) out[((nn * 12 + t) << 10) + i] = pd * inv;
    }
}

extern "C" void kernel_launch(void* const* d_in, const int* in_sizes, int n_in,
                              void* d_out, int out_size, void* d_ws, size_t ws_size,
                              hipStream_t stream)
{
    const float* x      = (const float*)d_in[0];
    const float* conv0w = (const float*)d_in[1];  // (64,12,3,3)
    const float* convw  = (const float*)d_in[2];  // (4,64,64,3,3)
    const float* convb  = (const float*)d_in[3];  // (5,64)
    const float* gammas = (const float*)d_in[4];  // (5,64)
    const float* betas  = (const float*)d_in[5];  // (5,64)
    const float* regw   = (const float*)d_in[6];  // (12,64,3,3)
    const float* regb   = (const float*)d_in[7];  // (12)
    const float* attw   = (const float*)d_in[8];  // (12,1024,1024)

    float* out = (float*)d_out;                   // (4,12,32,32)
    float* att = out + 4 * 12 * 1024;             // (4,12,1024,1024)

    float* ws    = (float*)d_ws;
    float* stats = ws;                            // 5 x 128
    float* bufX  = stats + 640;                   // (48, PS) padded input
    float* bufA  = bufX + 48 * PS;                // (256, PS) padded
    float* bufB  = bufA + 256 * PS;               // (256, PS) padded
    float* xf    = bufB + 256 * PS;               // (4,12,1024) flat
    // ci-chunk partials live in the att region of d_out (4 MB of its
    // 201 MB), dead by the time attention runs -> d_ws footprint is
    // byte-identical to the previously harness-verified kernel.
    float* part  = att;                           // (4, 4*COUT, 1024)

    // zero stats + all padded buffers (borders must be 0; ws is poisoned).
    // part/xf are fully overwritten -> no zeroing needed.
    (void)hipMemsetAsync(stats, 0,
                         (640 + 48 * PS + 2 * 256 * PS) * sizeof(float),
                         stream);

    pad_copy_kern<<<48, 256, 0, stream>>>(x, bufX);

    // ---- layer 0: conv 12->64 (3 ci per chunk), stats0, bn0 -> bufA holds h0
    conv3x3_part<3, 12, 64><<<1024, 256, 0, stream>>>(bufX, conv0w, part);
    combine_kern<64, true, true><<<256, 256, 0, stream>>>(part, convb, bufA, stats);
    bnrelu_kern<<<256, 256, 0, stream>>>(bufA, stats, gammas, betas);

    // ---- layer 1: bufA -> bufB
    conv3x3_part<16, 64, 64><<<1024, 256, 0, stream>>>(bufA, convw + 0 * 36864, part);
    combine_kern<64, true, true><<<256, 256, 0, stream>>>(part, convb + 64, bufB, stats + 128);
    bnrelu_kern<<<256, 256, 0, stream>>>(bufB, stats + 128, gammas + 64, betas + 64);

    // ---- layer 2: bufB -> bufA
    conv3x3_part<16, 64, 64><<<1024, 256, 0, stream>>>(bufB, convw + 1 * 36864, part);
    combine_kern<64, true, true><<<256, 256, 0, stream>>>(part, convb + 128, bufA, stats + 256);
    bnrelu_kern<<<256, 256, 0, stream>>>(bufA, stats + 256, gammas + 128, betas + 128);

    // ---- layer 3: bufA -> bufB
    conv3x3_part<16, 64, 64><<<1024, 256, 0, stream>>>(bufA, convw + 2 * 36864, part);
    combine_kern<64, true, true><<<256, 256, 0, stream>>>(part, convb + 192, bufB, stats + 384);
    bnrelu_kern<<<256, 256, 0, stream>>>(bufB, stats + 384, gammas + 192, betas + 192);

    // ---- layer 4: bufB -> bufA
    conv3x3_part<16, 64, 64><<<1024, 256, 0, stream>>>(bufB, convw + 3 * 36864, part);
    combine_kern<64, true, true><<<256, 256, 0, stream>>>(part, convb + 256, bufA, stats + 512);
    bnrelu_kern<<<256, 256, 0, stream>>>(bufA, stats + 512, gammas + 256, betas + 256);

    // ---- regressor: 64 -> 12, bufA -> xf (flat), no stats/bn
    conv3x3_part<16, 64, 12><<<192, 256, 0, stream>>>(bufA, regw, part);
    combine_kern<12, false, false><<<48, 256, 0, stream>>>(part, regb, xf, nullptr);

    attention_v3<<<3072, 256, 0, stream>>>(xf, attw, out, att);
}